// Round 2
// baseline (802.705 us; speedup 1.0000x reference)
//
#include <hip/hip_runtime.h>

#define N_NODES 50000
#define N_EDGES 800000

typedef __attribute__((ext_vector_type(8))) short short8;
typedef __attribute__((ext_vector_type(4))) float floatx4;

__device__ __forceinline__ float bf2f(short s) {
  unsigned int u = ((unsigned int)(unsigned short)s) << 16;
  return __builtin_bit_cast(float, u);
}
__device__ __forceinline__ short f2bf(float f) {
  unsigned int u = __builtin_bit_cast(unsigned int, f);
  unsigned int r = (u + 0x7FFFu + ((u >> 16) & 1u)) >> 16;
  return (short)r;
}
__device__ __forceinline__ float fsilu(float v) {
  return v / (1.f + __expf(-v));
}

// Convert h (f32) -> h_bf (bf16). 6.4M elements, 4 per thread.
__global__ void prep_h(const float* __restrict__ h, short* __restrict__ h_bf) {
  int id = blockIdx.x * 256 + threadIdx.x;   // 0..1.6M-1
  const float4 v = *(const float4*)(h + (size_t)id * 4);
  short4 t;
  t.x = f2bf(v.x); t.y = f2bf(v.y); t.z = f2bf(v.z); t.w = f2bf(v.w);
  *(short4*)(h_bf + (size_t)id * 4) = t;
}

// Repack f32 weight matrices [K,128] row-major into bf16 MFMA B-frag order:
// chunk = kt*512 + c*64 + lane; elems j=0..7 are W[kt*32 + (lane>>4)*8 + j][c*16 + (lane&15)]
__global__ void prep_weights(const float* __restrict__ eW1, const float* __restrict__ eW2,
                             const float* __restrict__ nW1, const float* __restrict__ nW2,
                             short* __restrict__ W1f, short* __restrict__ W2f,
                             short* __restrict__ N1f, short* __restrict__ N2f) {
  int id = blockIdx.x * 256 + threadIdx.x;   // 0..12287
  const float* src; short* dst; int ch;
  if (id < 4096)       { src = eW1; dst = W1f; ch = id; }
  else if (id < 6144)  { src = eW2; dst = W2f; ch = id - 4096; }
  else if (id < 10240) { src = nW1; dst = N1f; ch = id - 6144; }
  else                 { src = nW2; dst = N2f; ch = id - 10240; }
  int kt = ch >> 9;
  int c  = (ch >> 6) & 7;
  int l  = ch & 63;
  int q = l >> 4, n = l & 15;
  int k0 = kt * 32 + q * 8;
  int col = c * 16 + n;
  short tmp[8];
#pragma unroll
  for (int j = 0; j < 8; ++j) tmp[j] = f2bf(src[(k0 + j) * 128 + col]);
#pragma unroll
  for (int j = 0; j < 8; ++j) dst[ch * 8 + j] = tmp[j];
}

// Edge kernel: 64 edges/block, 256 threads (4 waves, 16 edge-rows each).
// LDS layout (shorts): X [64][264] at 0 (gather); M1 [64][136] overlays [0,8704);
// M2 [64][132] at [8704,17152). X dead after layer-1; M2 disjoint from M1.
__global__ void __launch_bounds__(256) edge_kernel(
    const short* __restrict__ h_bf, const int* __restrict__ idx,
    const short* __restrict__ W1f, const short* __restrict__ W2f,
    const float* __restrict__ eb1, const float* __restrict__ eb2,
    const float* __restrict__ aW, const float* __restrict__ ab,
    float* __restrict__ agg) {
  __shared__ __align__(16) short Smem[17152];
  __shared__ int rowid[64];
  const int tid = threadIdx.x;
  const int e0 = blockIdx.x * 64;
  if (tid < 64) rowid[tid] = idx[e0 + tid];
  // gather x = [h[row] | h[col]] -> X rows of 256 bf16 (stride 264)
#pragma unroll
  for (int i = 0; i < 8; ++i) {
    int id = i * 256 + tid;
    int e = id >> 5, ch = id & 31;
    int node = (ch < 16) ? idx[e0 + e] : idx[N_EDGES + e0 + e];
    const uint4 v = *(const uint4*)(h_bf + (size_t)node * 128 + (ch & 15) * 8);
    *(uint4*)(Smem + e * 264 + ch * 8) = v;
  }
  __syncthreads();
  const int w = tid >> 6, lane = tid & 63, q = lane >> 4, n = lane & 15;

  // ---- layer 1: [64,256] @ eW1 -> [64,128]
  floatx4 acc[8];
#pragma unroll
  for (int c = 0; c < 8; ++c) acc[c] = (floatx4){0.f, 0.f, 0.f, 0.f};
  {
    const short* Arow = Smem + (16 * w + n) * 264 + q * 8;
    const short8* B = (const short8*)W1f + lane;
#pragma unroll
    for (int kt = 0; kt < 8; ++kt) {
      short8 a = *(const short8*)(Arow + kt * 32);
#pragma unroll
      for (int c = 0; c < 8; ++c) {
        short8 b = B[kt * 512 + c * 64];
        acc[c] = __builtin_amdgcn_mfma_f32_16x16x32_bf16(a, b, acc[c], 0, 0, 0);
      }
    }
  }
  __syncthreads();  // all X reads done before M1 overwrites X
#pragma unroll
  for (int c = 0; c < 8; ++c) {
    float b1 = eb1[c * 16 + n];
#pragma unroll
    for (int j = 0; j < 4; ++j) {
      float v = fsilu(acc[c][j] + b1);
      Smem[(16 * w + q * 4 + j) * 136 + c * 16 + n] = f2bf(v);
    }
  }
  __syncthreads();

  // ---- layer 2: [64,128] @ eW2 -> [64,128]
  floatx4 acc2[8];
#pragma unroll
  for (int c = 0; c < 8; ++c) acc2[c] = (floatx4){0.f, 0.f, 0.f, 0.f};
  {
    const short* Arow = Smem + (16 * w + n) * 136 + q * 8;
    const short8* B = (const short8*)W2f + lane;
#pragma unroll
    for (int kt = 0; kt < 4; ++kt) {
      short8 a = *(const short8*)(Arow + kt * 32);
#pragma unroll
      for (int c = 0; c < 8; ++c) {
        short8 b = B[kt * 512 + c * 64];
        acc2[c] = __builtin_amdgcn_mfma_f32_16x16x32_bf16(a, b, acc2[c], 0, 0, 0);
      }
    }
  }
  // ---- attention gate + pack edge_feat*0.01 into M2 (disjoint from M1: no barrier)
  float sil[8][4];
  float p[4] = {0.f, 0.f, 0.f, 0.f};
#pragma unroll
  for (int c = 0; c < 8; ++c) {
    float b2 = eb2[c * 16 + n];
    float av = aW[c * 16 + n];
#pragma unroll
    for (int j = 0; j < 4; ++j) {
      float v = fsilu(acc2[c][j] + b2);
      sil[c][j] = v;
      p[j] += v * av;
    }
  }
#pragma unroll
  for (int m = 1; m < 16; m <<= 1) {
#pragma unroll
    for (int j = 0; j < 4; ++j) p[j] += __shfl_xor(p[j], m, 64);
  }
  float abv = ab[0];
  short* M2 = Smem + 8704;
#pragma unroll
  for (int j = 0; j < 4; ++j) {
    float att = 0.01f / (1.f + __expf(-(p[j] + abv)));  // fold /NORM_FACTOR here
#pragma unroll
    for (int c = 0; c < 8; ++c)
      M2[(16 * w + q * 4 + j) * 132 + c * 16 + n] = f2bf(sil[c][j] * att);
  }
  __syncthreads();
  // ---- scatter-add into agg (f32, device-scope atomics), coalesced 512B per edge
  const unsigned int* M2w = (const unsigned int*)M2;  // row stride 66 words
#pragma unroll
  for (int i = 0; i < 16; ++i) {
    int id = i * 256 + tid;
    int e = id >> 6, pc = id & 63;
    unsigned int v2 = M2w[e * 66 + pc];
    float lo = bf2f((short)(v2 & 0xFFFFu));
    float hi = bf2f((short)(v2 >> 16));
    float* dst = agg + (size_t)rowid[e] * 128 + pc * 2;
    atomicAdd(dst, lo);
    atomicAdd(dst + 1, hi);
  }
}

// Node kernel: 64 nodes/block. z=[h_bf,agg] [64][264] in LDS; M1 overlays [0,8704).
__global__ void __launch_bounds__(256) node_kernel(
    const float* __restrict__ h, const short* __restrict__ h_bf,
    const float* __restrict__ agg,
    const short* __restrict__ N1f, const short* __restrict__ N2f,
    const float* __restrict__ nb1, const float* __restrict__ nb2,
    float* __restrict__ out) {
  __shared__ __align__(16) short Smem[16896];
  const int tid = threadIdx.x;
  const int n0 = blockIdx.x * 64;
#pragma unroll
  for (int i = 0; i < 8; ++i) {
    int id = i * 256 + tid;
    int r = id >> 5, ch = id & 31;
    int rg = n0 + r;
    if (rg >= N_NODES) rg = N_NODES - 1;
    if (ch < 16) {
      *(uint4*)(Smem + r * 264 + ch * 8) =
          *(const uint4*)(h_bf + (size_t)rg * 128 + ch * 8);
    } else {
      const float4* s4 = (const float4*)(agg + (size_t)rg * 128 + (ch - 16) * 8);
      float4 v0 = s4[0], v1 = s4[1];
      short8 t;
      t[0] = f2bf(v0.x); t[1] = f2bf(v0.y); t[2] = f2bf(v0.z); t[3] = f2bf(v0.w);
      t[4] = f2bf(v1.x); t[5] = f2bf(v1.y); t[6] = f2bf(v1.z); t[7] = f2bf(v1.w);
      *(short8*)(Smem + r * 264 + ch * 8) = t;
    }
  }
  __syncthreads();
  const int w = tid >> 6, lane = tid & 63, q = lane >> 4, n = lane & 15;

  // ---- layer 1: [64,256] @ nW1
  floatx4 acc[8];
#pragma unroll
  for (int c = 0; c < 8; ++c) acc[c] = (floatx4){0.f, 0.f, 0.f, 0.f};
  {
    const short* Arow = Smem + (16 * w + n) * 264 + q * 8;
    const short8* B = (const short8*)N1f + lane;
#pragma unroll
    for (int kt = 0; kt < 8; ++kt) {
      short8 a = *(const short8*)(Arow + kt * 32);
#pragma unroll
      for (int c = 0; c < 8; ++c) {
        short8 b = B[kt * 512 + c * 64];
        acc[c] = __builtin_amdgcn_mfma_f32_16x16x32_bf16(a, b, acc[c], 0, 0, 0);
      }
    }
  }
  __syncthreads();
#pragma unroll
  for (int c = 0; c < 8; ++c) {
    float b1 = nb1[c * 16 + n];
#pragma unroll
    for (int j = 0; j < 4; ++j) {
      float v = fsilu(acc[c][j] + b1);
      Smem[(16 * w + q * 4 + j) * 136 + c * 16 + n] = f2bf(v);
    }
  }
  __syncthreads();

  // ---- layer 2: [64,128] @ nW2, residual epilogue (f32 h, f32 out)
  floatx4 acc2[8];
#pragma unroll
  for (int c = 0; c < 8; ++c) acc2[c] = (floatx4){0.f, 0.f, 0.f, 0.f};
  {
    const short* Arow = Smem + (16 * w + n) * 136 + q * 8;
    const short8* B = (const short8*)N2f + lane;
#pragma unroll
    for (int kt = 0; kt < 4; ++kt) {
      short8 a = *(const short8*)(Arow + kt * 32);
#pragma unroll
      for (int c = 0; c < 8; ++c) {
        short8 b = B[kt * 512 + c * 64];
        acc2[c] = __builtin_amdgcn_mfma_f32_16x16x32_bf16(a, b, acc2[c], 0, 0, 0);
      }
    }
  }
#pragma unroll
  for (int c = 0; c < 8; ++c) {
    int col = c * 16 + n;
    float b2 = nb2[col];
#pragma unroll
    for (int j = 0; j < 4; ++j) {
      int rg = n0 + 16 * w + q * 4 + j;
      if (rg < N_NODES) {
        size_t off = (size_t)rg * 128 + col;
        out[off] = acc2[c][j] + b2 + h[off];
      }
    }
  }
}

extern "C" void kernel_launch(void* const* d_in, const int* in_sizes, int n_in,
                              void* d_out, int out_size, void* d_ws, size_t ws_size,
                              hipStream_t stream) {
  (void)in_sizes; (void)n_in; (void)out_size; (void)ws_size;
  const float* h   = (const float*)d_in[0];
  const int*   idx = (const int*)d_in[1];
  const float* eW1 = (const float*)d_in[2];
  const float* eb1 = (const float*)d_in[3];
  const float* eW2 = (const float*)d_in[4];
  const float* eb2 = (const float*)d_in[5];
  const float* aW  = (const float*)d_in[6];
  const float* ab  = (const float*)d_in[7];
  const float* nW1 = (const float*)d_in[8];
  const float* nb1 = (const float*)d_in[9];
  const float* nW2 = (const float*)d_in[10];
  const float* nb2 = (const float*)d_in[11];
  float* out = (float*)d_out;

  // ws layout: agg f32 [50000,128] | h_bf bf16 [50000,128] | packed weights
  float* agg = (float*)d_ws;
  const size_t AGG_BYTES = (size_t)N_NODES * 128 * sizeof(float);   // 25.6 MB
  short* h_bf = (short*)((char*)d_ws + AGG_BYTES);
  const size_t HBF_BYTES = (size_t)N_NODES * 128 * sizeof(short);   // 12.8 MB
  short* W1f = (short*)((char*)d_ws + AGG_BYTES + HBF_BYTES);
  short* W2f = W1f + 32768;
  short* N1f = W2f + 16384;
  short* N2f = N1f + 32768;

  hipMemsetAsync(agg, 0, AGG_BYTES, stream);
  prep_h<<<(N_NODES * 128 / 4 + 255) / 256, 256, 0, stream>>>(h, h_bf);
  prep_weights<<<48, 256, 0, stream>>>(eW1, eW2, nW1, nW2, W1f, W2f, N1f, N2f);
  edge_kernel<<<N_EDGES / 64, 256, 0, stream>>>(h_bf, idx, W1f, W2f, eb1, eb2, aW, ab, agg);
  node_kernel<<<(N_NODES + 63) / 64, 256, 0, stream>>>(h, h_bf, agg, N1f, N2f, nb1, nb2, out);
}

// Round 3
// 487.204 us; speedup vs baseline: 1.6476x; 1.6476x over previous
//
#include <hip/hip_runtime.h>

#define N_NODES 50000
#define N_EDGES 800000

typedef __attribute__((ext_vector_type(8))) short short8;
typedef __attribute__((ext_vector_type(4))) float floatx4;

__device__ __forceinline__ float bf2f(short s) {
  unsigned int u = ((unsigned int)(unsigned short)s) << 16;
  return __builtin_bit_cast(float, u);
}
__device__ __forceinline__ short f2bf(float f) {
  unsigned int u = __builtin_bit_cast(unsigned int, f);
  unsigned int r = (u + 0x7FFFu + ((u >> 16) & 1u)) >> 16;
  return (short)r;
}
__device__ __forceinline__ float fsilu(float v) {
  return v / (1.f + __expf(-v));
}

// h (f32) -> h_bf (bf16), 4 elems/thread
__global__ void prep_h(const float* __restrict__ h, short* __restrict__ h_bf) {
  int id = blockIdx.x * 256 + threadIdx.x;
  const float4 v = *(const float4*)(h + (size_t)id * 4);
  short4 t;
  t.x = f2bf(v.x); t.y = f2bf(v.y); t.z = f2bf(v.z); t.w = f2bf(v.w);
  *(short4*)(h_bf + (size_t)id * 4) = t;
}

// f32 weights [K,128] row-major -> bf16 MFMA B-frag order
// chunk = kt*512 + c*64 + lane; elems j: W[kt*32 + (lane>>4)*8 + j][c*16 + (lane&15)]
__global__ void prep_weights(const float* __restrict__ eW1, const float* __restrict__ eW2,
                             const float* __restrict__ nW1, const float* __restrict__ nW2,
                             short* __restrict__ W1f, short* __restrict__ W2f,
                             short* __restrict__ N1f, short* __restrict__ N2f) {
  int id = blockIdx.x * 256 + threadIdx.x;   // 0..12287
  const float* src; short* dst; int ch;
  if (id < 4096)       { src = eW1; dst = W1f; ch = id; }
  else if (id < 6144)  { src = eW2; dst = W2f; ch = id - 4096; }
  else if (id < 10240) { src = nW1; dst = N1f; ch = id - 6144; }
  else                 { src = nW2; dst = N2f; ch = id - 10240; }
  int kt = ch >> 9;
  int c  = (ch >> 6) & 7;
  int l  = ch & 63;
  int q = l >> 4, n = l & 15;
  int k0 = kt * 32 + q * 8;
  int col = c * 16 + n;
  short tmp[8];
#pragma unroll
  for (int j = 0; j < 8; ++j) tmp[j] = f2bf(src[(k0 + j) * 128 + col]);
#pragma unroll
  for (int j = 0; j < 8; ++j) dst[ch * 8 + j] = tmp[j];
}

// Edge kernel: 64 edges/block, 512 threads (8 waves). Wave w: wq=w>>1 (m-tile),
// wc=w&1 (column half: chunks c=wc*4..wc*4+3). LDS: X [64][264] (gather),
// M1 [64][136] overlays X; patt[64][2] for cross-wave attention combine.
// Scatter: packed-bf16 atomics straight from registers.
__global__ void __launch_bounds__(512, 8) edge_kernel(
    const short* __restrict__ h_bf, const int* __restrict__ idx,
    const short* __restrict__ W1f, const short* __restrict__ W2f,
    const float* __restrict__ eb1, const float* __restrict__ eb2,
    const float* __restrict__ aW, const float* __restrict__ ab,
    unsigned short* __restrict__ agg) {
  __shared__ __align__(16) short Smem[16896];
  __shared__ float patt[64][2];
  __shared__ int rowid[64];
  const int tid = threadIdx.x;
  const int e0 = blockIdx.x * 64;
  if (tid < 64) rowid[tid] = idx[e0 + tid];
  // gather x = [h[row] | h[col]] -> X rows of 256 bf16 (stride 264)
#pragma unroll
  for (int i = 0; i < 4; ++i) {
    int id = i * 512 + tid;
    int e = id >> 5, ch = id & 31;
    int node = (ch < 16) ? idx[e0 + e] : idx[N_EDGES + e0 + e];
    *(uint4*)(Smem + e * 264 + ch * 8) =
        *(const uint4*)(h_bf + (size_t)node * 128 + (ch & 15) * 8);
  }
  __syncthreads();
  const int w = tid >> 6, lane = tid & 63, q = lane >> 4, n = lane & 15;
  const int wq = w >> 1, wc = w & 1;

  // ---- layer 1: [64,256] @ eW1, this wave computes rows 16wq.., cols wc*64..
  floatx4 acc[4];
#pragma unroll
  for (int cc = 0; cc < 4; ++cc) acc[cc] = (floatx4){0.f, 0.f, 0.f, 0.f};
  {
    const short* Arow = Smem + (16 * wq + n) * 264 + q * 8;
    const short8* B = (const short8*)W1f;
#pragma unroll
    for (int kt = 0; kt < 8; ++kt) {
      short8 a = *(const short8*)(Arow + kt * 32);
#pragma unroll
      for (int cc = 0; cc < 4; ++cc) {
        short8 b = B[kt * 512 + (wc * 4 + cc) * 64 + lane];
        acc[cc] = __builtin_amdgcn_mfma_f32_16x16x32_bf16(a, b, acc[cc], 0, 0, 0);
      }
    }
  }
  __syncthreads();  // all X reads done before M1 overwrites X
#pragma unroll
  for (int cc = 0; cc < 4; ++cc) {
    int c = wc * 4 + cc;
    float b1 = eb1[c * 16 + n];
#pragma unroll
    for (int j = 0; j < 4; ++j) {
      float v = fsilu(acc[cc][j] + b1);
      Smem[(16 * wq + q * 4 + j) * 136 + c * 16 + n] = f2bf(v);
    }
  }
  __syncthreads();

  // ---- layer 2: [64,128] @ eW2
  floatx4 acc2[4];
#pragma unroll
  for (int cc = 0; cc < 4; ++cc) acc2[cc] = (floatx4){0.f, 0.f, 0.f, 0.f};
  {
    const short* Arow = Smem + (16 * wq + n) * 136 + q * 8;
    const short8* B = (const short8*)W2f;
#pragma unroll
    for (int kt = 0; kt < 4; ++kt) {
      short8 a = *(const short8*)(Arow + kt * 32);
#pragma unroll
      for (int cc = 0; cc < 4; ++cc) {
        short8 b = B[kt * 512 + (wc * 4 + cc) * 64 + lane];
        acc2[cc] = __builtin_amdgcn_mfma_f32_16x16x32_bf16(a, b, acc2[cc], 0, 0, 0);
      }
    }
  }
  // ---- attention partial dot (this wave's 64 columns)
  float sil[4][4];
  float p[4] = {0.f, 0.f, 0.f, 0.f};
#pragma unroll
  for (int cc = 0; cc < 4; ++cc) {
    int c = wc * 4 + cc;
    float b2 = eb2[c * 16 + n];
    float av = aW[c * 16 + n];
#pragma unroll
    for (int j = 0; j < 4; ++j) {
      float v = fsilu(acc2[cc][j] + b2);
      sil[cc][j] = v;
      p[j] += v * av;
    }
  }
#pragma unroll
  for (int m = 1; m < 16; m <<= 1) {
#pragma unroll
    for (int j = 0; j < 4; ++j) p[j] += __shfl_xor(p[j], m, 64);
  }
  if (n == 0) {
#pragma unroll
    for (int j = 0; j < 4; ++j) patt[16 * wq + q * 4 + j][wc] = p[j];
  }
  __syncthreads();
  // ---- finish gate, scatter via packed-bf16 atomics (no M2 staging)
  float att[4];
  int rid[4];
  float abv = ab[0];
#pragma unroll
  for (int j = 0; j < 4; ++j) {
    int row = 16 * wq + q * 4 + j;
    att[j] = 0.01f / (1.f + __expf(-(patt[row][0] + patt[row][1] + abv)));
    rid[j] = rowid[row];
  }
  const bool neven = ((n & 1) == 0);
#pragma unroll
  for (int cc = 0; cc < 4; ++cc) {
    int colb = wc * 64 + cc * 16 + (n & ~1);
#pragma unroll
    for (int j = 0; j < 4; ++j) {
      float v = sil[cc][j] * att[j];
      float nbv = __shfl_xor(v, 1, 64);
      // even lanes issue j=0,1; odd lanes j=2,3 (same column pair, full issue width)
      if (neven == (j < 2)) {
        unsigned int lo = (unsigned short)(neven ? f2bf(v) : f2bf(nbv));
        unsigned int hi = (unsigned short)(neven ? f2bf(nbv) : f2bf(v));
        unsigned int pa = lo | (hi << 16);
        unsigned short* addr = agg + (size_t)rid[j] * 128 + colb;
        asm volatile("global_atomic_pk_add_bf16 %0, %1, off" :: "v"(addr), "v"(pa) : "memory");
      }
    }
  }
  asm volatile("s_waitcnt vmcnt(0)" ::: "memory");  // drain untracked asm atomics
}

// Node kernel: 64 nodes/block. z=[h_bf, agg(bf16)] [64][264] in LDS; M1 overlays.
__global__ void __launch_bounds__(256) node_kernel(
    const float* __restrict__ h, const short* __restrict__ h_bf,
    const short* __restrict__ agg,
    const short* __restrict__ N1f, const short* __restrict__ N2f,
    const float* __restrict__ nb1, const float* __restrict__ nb2,
    float* __restrict__ out) {
  __shared__ __align__(16) short Smem[16896];
  const int tid = threadIdx.x;
  const int n0 = blockIdx.x * 64;
#pragma unroll
  for (int i = 0; i < 8; ++i) {
    int id = i * 256 + tid;
    int r = id >> 5, ch = id & 31;
    int rg = n0 + r;
    if (rg >= N_NODES) rg = N_NODES - 1;
    const short* src = (ch < 16) ? (h_bf + (size_t)rg * 128 + ch * 8)
                                 : (agg + (size_t)rg * 128 + (ch - 16) * 8);
    *(uint4*)(Smem + r * 264 + ch * 8) = *(const uint4*)src;
  }
  __syncthreads();
  const int w = tid >> 6, lane = tid & 63, q = lane >> 4, n = lane & 15;

  // ---- layer 1: [64,256] @ nW1
  floatx4 acc[8];
#pragma unroll
  for (int c = 0; c < 8; ++c) acc[c] = (floatx4){0.f, 0.f, 0.f, 0.f};
  {
    const short* Arow = Smem + (16 * w + n) * 264 + q * 8;
    const short8* B = (const short8*)N1f + lane;
#pragma unroll
    for (int kt = 0; kt < 8; ++kt) {
      short8 a = *(const short8*)(Arow + kt * 32);
#pragma unroll
      for (int c = 0; c < 8; ++c) {
        short8 b = B[kt * 512 + c * 64];
        acc[c] = __builtin_amdgcn_mfma_f32_16x16x32_bf16(a, b, acc[c], 0, 0, 0);
      }
    }
  }
  __syncthreads();
#pragma unroll
  for (int c = 0; c < 8; ++c) {
    float b1 = nb1[c * 16 + n];
#pragma unroll
    for (int j = 0; j < 4; ++j) {
      float v = fsilu(acc[c][j] + b1);
      Smem[(16 * w + q * 4 + j) * 136 + c * 16 + n] = f2bf(v);
    }
  }
  __syncthreads();

  // ---- layer 2: [64,128] @ nW2, residual epilogue (f32 h, f32 out)
  floatx4 acc2[8];
#pragma unroll
  for (int c = 0; c < 8; ++c) acc2[c] = (floatx4){0.f, 0.f, 0.f, 0.f};
  {
    const short* Arow = Smem + (16 * w + n) * 136 + q * 8;
    const short8* B = (const short8*)N2f + lane;
#pragma unroll
    for (int kt = 0; kt < 4; ++kt) {
      short8 a = *(const short8*)(Arow + kt * 32);
#pragma unroll
      for (int c = 0; c < 8; ++c) {
        short8 b = B[kt * 512 + c * 64];
        acc2[c] = __builtin_amdgcn_mfma_f32_16x16x32_bf16(a, b, acc2[c], 0, 0, 0);
      }
    }
  }
#pragma unroll
  for (int c = 0; c < 8; ++c) {
    int col = c * 16 + n;
    float b2 = nb2[col];
#pragma unroll
    for (int j = 0; j < 4; ++j) {
      int rg = n0 + 16 * w + q * 4 + j;
      if (rg < N_NODES) {
        size_t off = (size_t)rg * 128 + col;
        out[off] = acc2[c][j] + b2 + h[off];
      }
    }
  }
}

extern "C" void kernel_launch(void* const* d_in, const int* in_sizes, int n_in,
                              void* d_out, int out_size, void* d_ws, size_t ws_size,
                              hipStream_t stream) {
  (void)in_sizes; (void)n_in; (void)out_size; (void)ws_size;
  const float* h   = (const float*)d_in[0];
  const int*   idx = (const int*)d_in[1];
  const float* eW1 = (const float*)d_in[2];
  const float* eb1 = (const float*)d_in[3];
  const float* eW2 = (const float*)d_in[4];
  const float* eb2 = (const float*)d_in[5];
  const float* aW  = (const float*)d_in[6];
  const float* ab  = (const float*)d_in[7];
  const float* nW1 = (const float*)d_in[8];
  const float* nb1 = (const float*)d_in[9];
  const float* nW2 = (const float*)d_in[10];
  const float* nb2 = (const float*)d_in[11];
  float* out = (float*)d_out;

  // ws layout: agg bf16 [50000,128] | h_bf bf16 [50000,128] | packed weights
  unsigned short* agg = (unsigned short*)d_ws;
  const size_t AGG_BYTES = (size_t)N_NODES * 128 * sizeof(short);   // 12.8 MB
  short* h_bf = (short*)((char*)d_ws + AGG_BYTES);
  const size_t HBF_BYTES = (size_t)N_NODES * 128 * sizeof(short);   // 12.8 MB
  short* W1f = (short*)((char*)d_ws + AGG_BYTES + HBF_BYTES);
  short* W2f = W1f + 32768;
  short* N1f = W2f + 16384;
  short* N2f = N1f + 32768;

  hipMemsetAsync(agg, 0, AGG_BYTES, stream);
  prep_h<<<(N_NODES * 128 / 4 + 255) / 256, 256, 0, stream>>>(h, h_bf);
  prep_weights<<<48, 256, 0, stream>>>(eW1, eW2, nW1, nW2, W1f, W2f, N1f, N2f);
  edge_kernel<<<N_EDGES / 64, 512, 0, stream>>>(h_bf, idx, W1f, W2f, eb1, eb2, aW, ab, agg);
  node_kernel<<<(N_NODES + 63) / 64, 256, 0, stream>>>(h, h_bf, (const short*)agg,
                                                       N1f, N2f, nb1, nb2, out);
}